// Round 5
// baseline (587.902 us; speedup 1.0000x reference)
//
#include <hip/hip_runtime.h>

#define NPTS   16384
#define KCODES 8192
#define DDIM   256
#define HWSZ   1024
#define CHW    (DDIM * HWSZ)          // 262144
#define OUT_ELEMS 4194304
#define LOSS_OFF  OUT_ELEMS
#define IDX_OFF   (OUT_ELEMS + 1)

#define PTB   32                 // points per block -> grid 512, 2 blocks/CU of work
#define CTILE 128                // codes per tile
#define NSUB  512                // 64 tiles x 8 K32 sub-chunks
#define XPITCH 264               // x f16 pitch (528 B -> 2-way bank alias, free)

// LDS arena: e-dbuf buf q in {0,1}: EH at q*16384, EL at q*16384+8192 (32 KB).
// X (prologue-only, DEAD after A-hoist) aliases it: XH at 0 (16896 B), XL at
// 16896 (16896 B). Arena = 33792 B; total block LDS ~36 KB  —  DELIBERATELY
// < 64 KB: R12 post-mortem says blocks with LDS > 64 KB get exclusive-CU
// placement (68 KB block -> occupancy 11.9% = 1 block/CU despite all other
// resources fitting 2). This kernel is the falsifiable test + the win.
#define ARENA_B 33792
#define XH_OFF  0
#define XL_OFF  16896

typedef _Float16 half_t;
typedef __attribute__((ext_vector_type(8))) _Float16 half8;
typedef __attribute__((ext_vector_type(4))) float     v4f;

union HU { _Float16 h; unsigned short u; };

#define EHI_WORDS  (256 * 8192)                 // ushorts (4 MB)
#define SE_OFF_B   (2 * EHI_WORDS * 2)          // byte offset of se[] in ws

#define GLD16(gp, lp) __builtin_amdgcn_global_load_lds( \
    (const __attribute__((address_space(1))) unsigned int*)(gp), \
    (__attribute__((address_space(3))) unsigned int*)(lp), 16, 0, 0)

// ---- prep: split emb to f16 hi/lo (bit-identical formula to R7 staging),
// plus se[k] = ||e_k||^2 (fp32).
// R13 layout: per (tile T, K32 sub-chunk ck2): an 8 KB image of 64 rows x
// 128 B. Row r' holds codes 2r' and 2r'+1 (32 elems each) as 8 granules of
// 8 ushorts; granule (c,g) at slot ((c&1)*4+g) ^ (r'&7). Linear-DMA-stageable,
// and vq's 16-lane b128 reads land 2 lanes/bank-group (free).
__global__ void prep_kernel(const float* __restrict__ emb,
                            unsigned short* __restrict__ ehi,
                            unsigned short* __restrict__ elo,
                            float* __restrict__ se)
{
    const int gw   = (blockIdx.x * 256 + threadIdx.x) >> 6;   // 0..1023
    const int lane = threadIdx.x & 63;
    for (int i = 0; i < 8; ++i) {
        const int c = gw * 8 + i;                             // code 0..8191
        const float4 v = *(const float4*)(emb + (size_t)c * DDIM + lane * 4);
        float ps = v.x * v.x;
        ps = fmaf(v.y, v.y, ps); ps = fmaf(v.z, v.z, ps); ps = fmaf(v.w, v.w, ps);
        float tot = ps;
        #pragma unroll
        for (int off = 1; off < 64; off <<= 1) tot += __shfl_xor(tot, off);
        if (lane == 0) se[c] = tot;
        const float E0 = v.x * 64.f, E1 = v.y * 64.f, E2 = v.z * 64.f, E3 = v.w * 64.f;
        const half_t h0 = (half_t)E0, h1 = (half_t)E1, h2 = (half_t)E2, h3 = (half_t)E3;
        const half_t l0 = (half_t)((E0 - (float)h0) * 2048.f);
        const half_t l1 = (half_t)((E1 - (float)h1) * 2048.f);
        const half_t l2 = (half_t)((E2 - (float)h2) * 2048.f);
        const half_t l3 = (half_t)((E3 - (float)h3) * 2048.f);
        HU a0, a1, a2, a3, b0, b1, b2, b3;
        a0.h = h0; a1.h = h1; a2.h = h2; a3.h = h3;
        b0.h = l0; b1.h = l1; b2.h = l2; b3.h = l3;
        const unsigned int uh0 = (unsigned)a0.u | ((unsigned)a1.u << 16);
        const unsigned int uh1 = (unsigned)a2.u | ((unsigned)a3.u << 16);
        const unsigned int ul0 = (unsigned)b0.u | ((unsigned)b1.u << 16);
        const unsigned int ul1 = (unsigned)b2.u | ((unsigned)b3.u << 16);
        // lane covers k = 4*lane .. 4*lane+3
        const int ck2 = lane >> 3;                // K32 sub-chunk 0..7
        const int g   = (lane >> 1) & 3;          // granule (8 k) within sub-chunk
        const int hf  = lane & 1;                 // 4-elem half of granule
        const int T   = c >> 7;
        const int row = (c & 127) >> 1;           // 0..63
        const int slot = (((c & 1) << 2) + g) ^ (row & 7);
        const size_t base = ((size_t)(T * 8 + ck2)) * 4096
                          + (size_t)row * 64 + slot * 8 + hf * 4;
        *(unsigned int*)&ehi[base]     = uh0;
        *(unsigned int*)&ehi[base + 2] = uh1;
        *(unsigned int*)&elo[base]     = ul0;
        *(unsigned int*)&elo[base + 2] = ul1;
    }
}

// m = x.e via 3 f16 MFMAs (exact pow2 scalings, R7-identical):
//   m = (hh + (xh.el + xl.eh)*2^-11) / 64
// dist = fl(fl(s+se) - 2m) fp32, lowest-index tie-break (proven R1-R7).
// R13: PTB 32 / 4 waves / grid 512 with ~36 KB LDS (< 64 KB) so TWO blocks
//   co-reside per CU (two independent barrier domains; one block's MFMA
//   covers the other's DMA/barrier stall). K32 staging granularity with the
//   paired-code row layout keeps reads 2-way-free and DMA linear. MFMA
//   K-slice order identical to R9 -> bit-identical results.
// NOTE: never pass a second __launch_bounds__ arg on this toolchain (R4).
__launch_bounds__(256)
__global__ void vq_kernel(const float* __restrict__ x,
                          const unsigned short* __restrict__ ehi,
                          const unsigned short* __restrict__ elo,
                          const float* __restrict__ wse,
                          const float* __restrict__ emb,
                          float* __restrict__ out)
{
    __shared__ __align__(16) char ldsA[ARENA_B];
    __shared__ float  ldsRS[8][33];
    __shared__ float  ldsS[PTB];
    __shared__ float  ldsFD[4][32];
    __shared__ int    ldsFI[4][32];
    __shared__ int    ldsI[PTB];
    __shared__ double ldsL[4];

    const int t    = threadIdx.x;
    const int lane = t & 63;
    const int w    = t >> 6;          // 0..3
    const int n0   = blockIdx.x * PTB;
    const int b    = n0 / HWSZ;
    const int hw0  = n0 % HWSZ;
    const float* xs = x + (size_t)b * CHW + hw0;   // xs[c*HWSZ + p]

    unsigned short* XHp = (unsigned short*)(ldsA + XH_OFF);
    unsigned short* XLp = (unsigned short*)(ldsA + XL_OFF);

    // ---- e sub-chunk DMA staging: 16 KB/sub-chunk (8 hi + 8 lo);
    //      waves 0-1 hi, 2-3 lo; 4x1KB calls per wave ----
    const int part = (w & 1) * 4096;               // byte sub-range of the 8 KB half
    #define STAGE(s, q) do { \
        const char* _g = (const char*)((w < 2) ? ehi : elo) \
                       + (size_t)(s) * 8192 + part + lane * 16; \
        char* _l = ldsA + (size_t)(q) * 16384 + ((w < 2) ? 0 : 8192) + part; \
        GLD16(_g,          _l); \
        GLD16(_g + 1024,   _l + 1024); \
        GLD16(_g + 2048,   _l + 2048); \
        GLD16(_g + 3072,   _l + 3072); \
    } while (0)

    // ---- prologue: stage x split hi/lo (f16), accumulate s[p]=||x_p||^2 ----
    // (X lives in the arena; NO e-staging before the post-hoist drain.)
    {
        const int p   = t & 31;
        const int seg = t >> 5;       // 0..7
        float a = 0.f;
        for (int i = 0; i < 32; ++i) {
            const int c = seg * 32 + i;
            const float v = xs[(size_t)c * HWSZ + p];
            const half_t hh = (half_t)v;
            const half_t hl = (half_t)((v - (float)hh) * 2048.0f);
            HU u0; u0.h = hh; XHp[p * XPITCH + c] = u0.u;
            HU u1; u1.h = hl; XLp[p * XPITCH + c] = u1.u;
            a = fmaf(v, v, a);
        }
        ldsRS[seg][p] = a;
    }
    __syncthreads();
    if (t < PTB) {
        float s = 0.f;
        for (int g = 0; g < 8; ++g) s += ldsRS[g][t];
        ldsS[t] = s;
    }
    __syncthreads();

    const int q32 = w * 32;           // code-quarter base within tile
    const int ln  = lane & 15;
    const int qd  = lane >> 4;        // 0..3 (k-granule within K32 sub-chunk)

    float s_frag[8];
    #pragma unroll
    for (int pbi = 0; pbi < 2; ++pbi)
        #pragma unroll
        for (int r = 0; r < 4; ++r)
            s_frag[pbi * 4 + r] = ldsS[pbi * 16 + qd * 4 + r];

    // ---- A-fragment hoist: the block's 32 x-rows, full K=256, hi+lo (128 VGPR) ----
    half8 aH[2][4][2], aL[2][4][2];   // [pt-block][ck][kk]
    #pragma unroll
    for (int pb = 0; pb < 2; ++pb)
        #pragma unroll
        for (int ck = 0; ck < 4; ++ck)
            #pragma unroll
            for (int kk = 0; kk < 2; ++kk) {
                const int ka = ck * 64 + kk * 32 + qd * 8;
                aH[pb][ck][kk] = *(const half8*)&XHp[(pb * 16 + ln) * XPITCH + ka];
                aL[pb][ck][kk] = *(const half8*)&XLp[(pb * 16 + ln) * XPITCH + ka];
            }
    // X region DEAD; e-bufs alias it. __syncthreads (lgkmcnt(0) in all waves)
    // orders all X reads before the DMA below.
    __syncthreads();

    STAGE(0, 0);   // bootstrap sub-chunk 0 (drained by first loop __syncthreads)

    // loop-invariant read offsets (ushort units) into the 8 KB sub-chunk image:
    //   row of code (q32+ln) = (q32+ln)>>1; slot = ((ln&1)*4 + qd) ^ (ln>>1)
    //   (q32 is a multiple of 32 so row&7 == ln>>1). +16-code row: +8 rows.
    const int offL = ((q32 + ln) >> 1) * 64 + (((((ln & 1) << 2) + qd) ^ (ln >> 1)) << 3);
    const int offH = offL + 512;

    float best_d[8]; int best_i[8];
    #pragma unroll
    for (int i = 0; i < 8; ++i) { best_d[i] = 3.4e38f; best_i[i] = 0; }

    v4f acc_hh[2][2], acc_hl[2][2];
    float se0 = 0.f, se1 = 0.f;

    // one K32 sub-chunk: 4 b128 reads + 12 MFMAs, order identical to R9's kk body
    #define SUBSTEP(CK, KK, C8) do { \
        __syncthreads();   /* buf[C8&1] DMA drained; prior readers of it done */ \
        { const int s_ = tile * 8 + (C8); \
          if (s_ + 1 < NSUB) STAGE(s_ + 1, ((C8) + 1) & 1); } \
        if ((C8) == 4) {   /* prefetch se for this tile's finalize */ \
            se0 = wse[tile * CTILE + q32 + ln]; \
            se1 = wse[tile * CTILE + q32 + 16 + ln]; \
        } \
        { const unsigned short* EHp = (const unsigned short*)(ldsA + ((C8) & 1) * 16384); \
          const unsigned short* ELp = (const unsigned short*)(ldsA + ((C8) & 1) * 16384 + 8192); \
          const half8 bh0 = *(const half8*)&EHp[offL]; \
          const half8 bh1 = *(const half8*)&EHp[offH]; \
          const half8 bl0 = *(const half8*)&ELp[offL]; \
          const half8 bl1 = *(const half8*)&ELp[offH]; \
          acc_hh[0][0] = __builtin_amdgcn_mfma_f32_16x16x32_f16(aH[0][CK][KK], bh0, acc_hh[0][0], 0, 0, 0); \
          acc_hh[0][1] = __builtin_amdgcn_mfma_f32_16x16x32_f16(aH[0][CK][KK], bh1, acc_hh[0][1], 0, 0, 0); \
          acc_hh[1][0] = __builtin_amdgcn_mfma_f32_16x16x32_f16(aH[1][CK][KK], bh0, acc_hh[1][0], 0, 0, 0); \
          acc_hh[1][1] = __builtin_amdgcn_mfma_f32_16x16x32_f16(aH[1][CK][KK], bh1, acc_hh[1][1], 0, 0, 0); \
          acc_hl[0][0] = __builtin_amdgcn_mfma_f32_16x16x32_f16(aH[0][CK][KK], bl0, acc_hl[0][0], 0, 0, 0); \
          acc_hl[0][1] = __builtin_amdgcn_mfma_f32_16x16x32_f16(aH[0][CK][KK], bl1, acc_hl[0][1], 0, 0, 0); \
          acc_hl[1][0] = __builtin_amdgcn_mfma_f32_16x16x32_f16(aH[1][CK][KK], bl0, acc_hl[1][0], 0, 0, 0); \
          acc_hl[1][1] = __builtin_amdgcn_mfma_f32_16x16x32_f16(aH[1][CK][KK], bl1, acc_hl[1][1], 0, 0, 0); \
          acc_hl[0][0] = __builtin_amdgcn_mfma_f32_16x16x32_f16(aL[0][CK][KK], bh0, acc_hl[0][0], 0, 0, 0); \
          acc_hl[0][1] = __builtin_amdgcn_mfma_f32_16x16x32_f16(aL[0][CK][KK], bh1, acc_hl[0][1], 0, 0, 0); \
          acc_hl[1][0] = __builtin_amdgcn_mfma_f32_16x16x32_f16(aL[1][CK][KK], bh0, acc_hl[1][0], 0, 0, 0); \
          acc_hl[1][1] = __builtin_amdgcn_mfma_f32_16x16x32_f16(aL[1][CK][KK], bh1, acc_hl[1][1], 0, 0, 0); \
        } \
    } while (0)

    for (int tile = 0; tile < 64; ++tile) {
        #pragma unroll
        for (int i = 0; i < 2; ++i)
            #pragma unroll
            for (int j = 0; j < 2; ++j)
                #pragma unroll
                for (int r = 0; r < 4; ++r) { acc_hh[i][j][r] = 0.f; acc_hl[i][j][r] = 0.f; }

        SUBSTEP(0, 0, 0);
        SUBSTEP(0, 1, 1);
        SUBSTEP(1, 0, 2);
        SUBSTEP(1, 1, 3);
        SUBSTEP(2, 0, 4);
        SUBSTEP(2, 1, 5);
        SUBSTEP(3, 0, 6);
        SUBSTEP(3, 1, 7);

        // ---- tile finalize: dist = fl(fl(s+se) - 2m), ascending code order ----
        {
            const int tb = tile * CTILE;
            #pragma unroll
            for (int csi = 0; csi < 2; ++csi) {
                const float se   = csi ? se1 : se0;
                const int   code = tb + q32 + csi * 16 + ln;
                #pragma unroll
                for (int pbi = 0; pbi < 2; ++pbi)
                    #pragma unroll
                    for (int r = 0; r < 4; ++r) {
                        const float m  = fmaf(acc_hl[pbi][csi][r], 4.8828125e-4f,
                                              acc_hh[pbi][csi][r]) * 0.015625f;
                        const float T  = s_frag[pbi * 4 + r] + se;
                        const float dd = fmaf(-2.0f, m, T);
                        const int   s  = pbi * 4 + r;
                        if (dd < best_d[s]) { best_d[s] = dd; best_i[s] = code; }
                    }
            }
        }
    }

    // ---- argmin reduce: butterfly over the 16-lane col group (lexicographic) ----
    #pragma unroll
    for (int off = 1; off < 16; off <<= 1) {
        #pragma unroll
        for (int s = 0; s < 8; ++s) {
            const float d2 = __shfl_xor(best_d[s], off);
            const int   i2 = __shfl_xor(best_i[s], off);
            if (d2 < best_d[s] || (d2 == best_d[s] && i2 < best_i[s])) {
                best_d[s] = d2; best_i[s] = i2;
            }
        }
    }
    if (ln == 0) {
        #pragma unroll
        for (int pbi = 0; pbi < 2; ++pbi)
            #pragma unroll
            for (int r = 0; r < 4; ++r) {
                ldsFD[w][pbi * 16 + qd * 4 + r] = best_d[pbi * 4 + r];
                ldsFI[w][pbi * 16 + qd * 4 + r] = best_i[pbi * 4 + r];
            }
    }
    __syncthreads();
    if (t < PTB) {
        float bd = 3.4e38f; int bi = 0;
        #pragma unroll
        for (int qq = 0; qq < 4; ++qq) {      // ascending q32 (lexicographic-safe)
            const float d2 = ldsFD[qq][t];
            const int   i2 = ldsFI[qq][t];
            if (d2 < bd || (d2 == bd && i2 < bi)) { bd = d2; bi = i2; }
        }
        ldsI[t] = bi;
        out[(size_t)IDX_OFF + n0 + t] = (float)bi;
    }
    __syncthreads();

    // ---- epilogue: gather e row, straight-through out, loss partial ----
    double lsum = 0.0;
    {
        const int p  = t & 31;
        const int cg = t >> 5;               // 0..7
        const int row = ldsI[p];
        const float* erow = emb + (size_t)row * DDIM;
        float* ob = out + (size_t)b * CHW + hw0 + p;
        for (int q = 0; q < 32; ++q) {
            const int c = cg * 32 + q;
            const float e  = erow[c];
            const float xx = xs[(size_t)c * HWSZ + p];
            const float diff = e - xx;             // fl(x_q - xt)
            ob[(size_t)c * HWSZ] = xx + diff;      // straight-through rounding
            lsum += (double)diff * (double)diff;
        }
    }
    #pragma unroll
    for (int off = 32; off > 0; off >>= 1)
        lsum += __shfl_xor(lsum, off);
    if ((t & 63) == 0) ldsL[t >> 6] = lsum;
    __syncthreads();
    if (t == 0) {
        double tot = 0.0;
        #pragma unroll
        for (int wv = 0; wv < 4; ++wv) tot += ldsL[wv];
        atomicAdd(&out[LOSS_OFF], (float)(tot * (1.25 / 4194304.0)));
    }
}

extern "C" void kernel_launch(void* const* d_in, const int* in_sizes, int n_in,
                              void* d_out, int out_size, void* d_ws, size_t ws_size,
                              hipStream_t stream) {
    (void)in_sizes; (void)n_in; (void)out_size; (void)ws_size;
    const float* x   = (const float*)d_in[0];
    const float* emb = (const float*)d_in[1];
    float* out = (float*)d_out;
    unsigned short* ehi = (unsigned short*)d_ws;
    unsigned short* elo = ehi + EHI_WORDS;
    float*          wse = (float*)((char*)d_ws + SE_OFF_B);
    hipMemsetAsync((char*)d_out + (size_t)LOSS_OFF * sizeof(float), 0, sizeof(float), stream);
    prep_kernel<<<256, 256, 0, stream>>>(emb, ehi, elo, wse);
    vq_kernel<<<NPTS / PTB, 256, 0, stream>>>(x, ehi, elo, wse, emb, out);
}